// Round 1
// baseline (1053.740 us; speedup 1.0000x reference)
//
#include <hip/hip_runtime.h>
#include <math.h>

// Problem constants (from reference): B=8, T=527, V=50257, L=512
#define NV 50257
#define TSEQ 527
#define ROWS_PER_B 511   // shifted sequence length
#define NB 8
#define ROW_OFFSET 15    // MAX_TOPIC_LEN + SEQ_LEN
#define LLEN 512
#define NEG_BIG (-3.402823466e38f)

// Online-softmax update: (m,s) <- include x
__device__ inline void upd(float x, float& m, float& s) {
    float M = fmaxf(m, x);
    // when x <= m: __expf(m-M)=1 -> s += exp(x-M). Branchless, predication-friendly.
    s = s * __expf(m - M) + __expf(x - M);
    m = M;
}

// Combine two (m,s) online-softmax states
__device__ inline void comb(float& m, float& s, float m2, float s2) {
    float M = fmaxf(m, m2);
    s = s * __expf(m - M) + s2 * __expf(m2 - M);
    m = M;
}

__global__ __launch_bounds__(256) void row_nll_kernel(
        const float* __restrict__ outputs,
        const int*   __restrict__ targets,
        float*       __restrict__ nll) {
    const int row = blockIdx.x;              // 0..4087
    const int b   = row / ROWS_PER_B;
    const int t   = row - b * ROWS_PER_B;    // 0..510
    const float* rp = outputs + (size_t)(b * TSEQ + ROW_OFFSET + t) * (size_t)NV;
    const int tid = threadIdx.x;

    // Peel to 16B alignment for dwordx4 body loads (row base is only 4B-aligned).
    const int head = (int)(((16u - ((unsigned)(uintptr_t)rp & 15u)) & 15u) >> 2); // 0..3
    const int nbody = (NV - head) >> 2;        // # of float4 in body
    const int tail_start = head + (nbody << 2);
    const int ntail = NV - tail_start;         // 0..3

    // 4 independent online states for ILP + one scalar state for head/tail
    float m0 = NEG_BIG, s0 = 0.f;
    float4 m4 = make_float4(NEG_BIG, NEG_BIG, NEG_BIG, NEG_BIG);
    float4 s4 = make_float4(0.f, 0.f, 0.f, 0.f);

    if (tid < head) upd(rp[tid], m0, s0);

    const float4* bp = (const float4*)(rp + head);
    for (int i = tid; i < nbody; i += 256) {
        float4 x = bp[i];
        upd(x.x, m4.x, s4.x);
        upd(x.y, m4.y, s4.y);
        upd(x.z, m4.z, s4.z);
        upd(x.w, m4.w, s4.w);
    }

    if (tid < ntail) upd(rp[tail_start + tid], m0, s0);

    // fold 4 vector states + scalar state
    comb(m0, s0, m4.x, s4.x);
    comb(m0, s0, m4.y, s4.y);
    comb(m0, s0, m4.z, s4.z);
    comb(m0, s0, m4.w, s4.w);

    // wave (64-lane) butterfly-ish reduce via shfl_down
    #pragma unroll
    for (int off = 32; off > 0; off >>= 1) {
        float mo = __shfl_down(m0, off);
        float so = __shfl_down(s0, off);
        comb(m0, s0, mo, so);
    }

    __shared__ float sm[4], ss[4];
    const int wave = tid >> 6, lane = tid & 63;
    if (lane == 0) { sm[wave] = m0; ss[wave] = s0; }
    __syncthreads();
    if (tid == 0) {
        float M = sm[0], S = ss[0];
        #pragma unroll
        for (int w = 1; w < 4; ++w) comb(M, S, sm[w], ss[w]);
        const int label = targets[b * LLEN + t + 1];   // shift_labels = targets[:,1:]
        const float lt = rp[label];
        // log_softmax at label: lt - M - log(S); nll = -(that)
        nll[row] = -(lt - M - logf(S));
    }
}

__global__ __launch_bounds__(256) void finalize_kernel(
        const float* __restrict__ nll,
        const int*   __restrict__ ratings,
        const int*   __restrict__ stage,
        float*       __restrict__ out) {
    const int tid = threadIdx.x;
    __shared__ float ce_sh[NB];
    __shared__ float tmp[4];
    const int wave = tid >> 6, lane = tid & 63;

    for (int b = 0; b < NB; ++b) {
        float local = 0.f;
        for (int i = tid; i < ROWS_PER_B; i += 256) local += nll[b * ROWS_PER_B + i];
        #pragma unroll
        for (int off = 32; off > 0; off >>= 1) local += __shfl_down(local, off);
        if (lane == 0) tmp[wave] = local;
        __syncthreads();
        if (tid == 0) ce_sh[b] = tmp[0] + tmp[1] + tmp[2] + tmp[3];
        __syncthreads();  // protect tmp reuse next iteration
    }

    if (tid == 0) {
        const int thresh = (stage[0] == 1) ? 4 : 3;
        float acc = 0.f;
        #pragma unroll
        for (int b = 0; b < NB; ++b) {
            float ce = ce_sh[b] / (float)ROWS_PER_B;
            float p  = expf(-ce);
            float y  = (ratings[b] > thresh) ? 1.f : 0.f;
            acc += -y * logf(p + 1e-10f) - (1.f - y) * logf(1.f - p + 1e-10f);
        }
        out[0] = acc / (float)NB;
    }
}

extern "C" void kernel_launch(void* const* d_in, const int* in_sizes, int n_in,
                              void* d_out, int out_size, void* d_ws, size_t ws_size,
                              hipStream_t stream) {
    const float* outputs = (const float*)d_in[0];   // (8, 527, 50257) fp32
    const int*   targets = (const int*)d_in[1];     // (8, 512) int
    const int*   ratings = (const int*)d_in[2];     // (8,) int32
    const int*   stage   = (const int*)d_in[3];     // scalar int
    float* out = (float*)d_out;
    float* nll = (float*)d_ws;                      // 4088 floats of scratch

    row_nll_kernel<<<NB * ROWS_PER_B, 256, 0, stream>>>(outputs, targets, nll);
    finalize_kernel<<<1, 256, 0, stream>>>(nll, ratings, stage, out);
}